// Round 6
// baseline (83.702 us; speedup 1.0000x reference)
//
#include <hip/hip_runtime.h>
#include <math.h>
#include <float.h>

#define MAX_DET 25
#define IOU_THRES 0.7f
#define MAX_WH 7680.0f
#define TOPK 256
#define MCAP 512
#define CPB 64              // candidates per decode block
#define DEC_F (CPB * 85)    // 5440 floats staged per block
#define DEC_F4 (DEC_F / 4)  // 1360 float4

__device__ __forceinline__ float sigm(float v) {
#pragma clang fp contract(off)
    return 1.0f / (1.0f + expf(-v));
}

// ---------------- Decode: LDS-staged, fully coalesced float4 reads ----------------
template<int NY, int NX>
__device__ __forceinline__ void decode_body(
    int blk, const float* __restrict__ x, const float* __restrict__ anch,
    float* __restrict__ confW, float* __restrict__ boxW, float* sx)
{
#pragma clang fp contract(off)
    constexpr int HW = NY * NX;
    constexpr int NPC = 3 * HW;
    const int tid = threadIdx.x;

    // stage 64 candidates (contiguous 21.76 KB) via float4
    const float4* src = (const float4*)(x + (long)blk * DEC_F);
    float4* dst = (float4*)sx;
#pragma unroll
    for (int it = 0; it < 6; ++it) {
        int i = tid + it * 256;
        if (i < DEC_F4) dst[i] = src[i];
    }
    __syncthreads();

    const int lane = tid & 63, wave = tid >> 6;
    const int grp = lane >> 4, l16 = lane & 15;
#pragma unroll
    for (int r = 0; r < 4; ++r) {
        int c = wave * 16 + r * 4 + grp;
        const float* row = sx + c * 85;

        float bv = -FLT_MAX; int bc = 0;
#pragma unroll
        for (int j = 0; j < 5; ++j) {
            float v = row[5 + l16 + 16 * j];
            if (v > bv) { bv = v; bc = l16 + 16 * j; }
        }
#pragma unroll
        for (int off = 8; off; off >>= 1) {
            float ov = __shfl_xor(bv, off);
            int   oc = __shfl_xor(bc, off);
            if (ov > bv || (ov == bv && oc < bc)) { bv = ov; bc = oc; }
        }
        if (l16 == 0) {
            float v0 = row[0], v1 = row[1], v2 = row[2], v3 = row[3], v4 = row[4];
            int gl = blk * CPB + c;          // candidate index within level
            int i   = gl % NPC;
            int a   = i / HW;
            int rem = i - a * HW;
            int gy  = rem / NX;
            int gx  = rem - gy * NX;

            float conf = sigm(bv) * sigm(v4);
            float cx = sigm(v0) * 2.0f + ((float)gx - 0.5f);
            float cy = sigm(v1) * 2.0f + ((float)gy - 0.5f);
            float tw = sigm(v2) * 2.0f, th = sigm(v3) * 2.0f;
            float w = (tw * tw) * anch[a * 2 + 0];
            float h = (th * th) * anch[a * 2 + 1];
            float x1 = cx - w / 2.0f, y1 = cy - h / 2.0f;
            float x2 = cx + w / 2.0f, y2 = cy + h / 2.0f;
            float offc = (float)bc * MAX_WH;

            confW[gl] = conf;
            *reinterpret_cast<float4*>(boxW + (long)gl * 4) =
                make_float4(x1 + offc, y1 + offc, x2 + offc, y2 + offc);
        }
    }
}

__global__ __launch_bounds__(256) void decode_all_kernel(
    const float* __restrict__ x0, const float* __restrict__ x1, const float* __restrict__ x2,
    const float* __restrict__ anch, float* __restrict__ confW, float* __restrict__ boxW)
{
    __shared__ float sx[DEC_F];
    int bid = blockIdx.x;
    if (bid < 4800)       decode_body<80, 80>(bid,        x0, anch + 0,  confW,          boxW,              sx);
    else if (bid < 6000)  decode_body<40, 40>(bid - 4800, x1, anch + 6,  confW + 307200, boxW + 307200L*4,  sx);
    else                  decode_body<20, 20>(bid - 6000, x2, anch + 12, confW + 384000, boxW + 384000L*4,  sx);
}

// ---------------- Fused per-group: radix-select + reg-resident NMS ----------------
struct LvlParams {
    const float* feat;
    long candOff;
    long outOff;
    int npc, ny, nx, C;
};

template<int NPC>
__device__ __forceinline__ void run_group(
    const float* __restrict__ gconf, const float* __restrict__ boxW, long base4,
    float* sconf, unsigned long long* sk, unsigned* hist, float (*sbox)[4],
    int* selIdx, int* selValid, unsigned* wtot /*16*/, unsigned* misc /*4*/,
    int grp, int2* __restrict__ sel)
{
#pragma clang fp contract(off)
    const int tid = threadIdx.x;
    const int lane = tid & 63;
    const int wid = tid >> 6;

    // stage conf in LDS (vectorized, coalesced)
    const float4* gc4 = (const float4*)gconf;
    float4* sc4 = (float4*)sconf;
    for (int i = tid; i < NPC / 4; i += 1024) sc4[i] = gc4[i];
    if (tid < MAX_DET) selValid[tid] = 0;
    if (tid == 0) misc[0] = 0;

    // ---- exact top-TOPK threshold via 2-pass radix histogram ----
    unsigned B = 0, B2 = 0, K2 = 0;
    for (int pass = 0; pass < 2; ++pass) {
        for (int i = tid; i < 2048; i += 1024) hist[i] = 0;
        __syncthreads();
        for (int i = tid; i < NPC; i += 1024) {
            unsigned bits = __float_as_uint(sconf[i]);
            if (pass == 0) atomicAdd(&hist[bits >> 19], 1u);
            else if ((bits >> 19) == B) atomicAdd(&hist[(bits >> 8) & 2047u], 1u);
        }
        __syncthreads();
        unsigned part = hist[tid * 2] + hist[tid * 2 + 1];
        unsigned s = part;
#pragma unroll
        for (int d = 1; d < 64; d <<= 1) {
            unsigned v = __shfl_down(s, d);
            if (lane < 64 - d) s += v;
        }
        if (lane == 0) wtot[wid] = s;
        __syncthreads();
        unsigned S = s;
        for (int w = wid + 1; w < 16; ++w) S += wtot[w];
        unsigned Ktgt = (pass == 0) ? TOPK : K2;
        if (S >= Ktgt && S - part < Ktgt) {     // unique crossing thread
            unsigned acc = S - part;
            for (int i = 1; i >= 0; --i) {
                unsigned h = hist[tid * 2 + i];
                acc += h;
                if (acc >= Ktgt) { misc[2] = (unsigned)(tid * 2 + i); misc[3] = acc - h; break; }
            }
        }
        __syncthreads();
        if (pass == 0) { B = misc[2]; K2 = Ktgt - misc[3]; }
        else           { B2 = misc[2]; }
        __syncthreads();
    }
    unsigned T = (B << 19) | (B2 << 8);

    // ---- collect {bits >= T} into LDS key list ----
    for (int i = tid; i < NPC; i += 1024) {
        unsigned bits = __float_as_uint(sconf[i]);
        if (bits >= T) {
            unsigned pos = atomicAdd(&misc[0], 1u);
            if (pos < MCAP)
                sk[pos] = ((unsigned long long)bits << 32) | (unsigned)(~i);
        }
    }
    __syncthreads();
    unsigned cn = misc[0];
    int n = (cn < (unsigned)MCAP) ? (int)cn : MCAP;

    // ---- prefetch boxes for all collected slots ----
    for (int i = tid; i < n; i += 1024) {
        int idx = (int)(~(unsigned)sk[i]);
        const float4 bb4 = *reinterpret_cast<const float4*>(boxW + base4 + (long)idx * 4);
        sbox[i][0] = bb4.x; sbox[i][1] = bb4.y; sbox[i][2] = bb4.z; sbox[i][3] = bb4.w;
    }
    __syncthreads();

    // ---- wave-0 register-resident selection-sort NMS (no block barriers) ----
    if (tid < 64) {
        unsigned long long kreg[8];
#pragma unroll
        for (int j = 0; j < 8; ++j) {
            int s = tid + 64 * j;
            kreg[j] = (s < n) ? sk[s] : 0ULL;
        }
        float ex1 = 0.f, ey1 = 0.f, ex2 = 0.f, ey2 = 0.f;  // lane t holds selected box t
        int k = 0;
        while (k < MAX_DET) {
            // 64-lane argmax over remaining keys (unique -> deterministic; tie conf -> smaller idx)
            unsigned long long mk = kreg[0]; int ms = tid;
#pragma unroll
            for (int j = 1; j < 8; ++j)
                if (kreg[j] > mk) { mk = kreg[j]; ms = tid + 64 * j; }
#pragma unroll
            for (int off = 32; off; off >>= 1) {
                unsigned long long ok = __shfl_xor(mk, off);
                int os = __shfl_xor(ms, off);
                if (ok > mk) { mk = ok; ms = os; }
            }
            if (mk == 0ULL) break;          // exhausted
            // owner removes the winner (static indices only)
#pragma unroll
            for (int j = 0; j < 8; ++j)
                if (ms == tid + 64 * j) kreg[j] = 0ULL;

            float cx1 = sbox[ms][0], cy1 = sbox[ms][1];
            float cx2 = sbox[ms][2], cy2 = sbox[ms][3];
            bool rej = false;
            if (tid < k) {
                float ltx = fmaxf(ex1, cx1), lty = fmaxf(ey1, cy1);
                float rbx = fminf(ex2, cx2), rby = fminf(ey2, cy2);
                float ww = fmaxf(rbx - ltx, 0.0f), hh = fmaxf(rby - lty, 0.0f);
                float inter = ww * hh;
                float area1 = (ex2 - ex1) * (ey2 - ey1);
                float area2 = (cx2 - cx1) * (cy2 - cy1);
                float iou = inter / (area1 + area2 - inter);
                rej = iou > IOU_THRES;
            }
            rej = __any(rej);
            if (!rej) {
                if (tid == k) { ex1 = cx1; ey1 = cy1; ex2 = cx2; ey2 = cy2; }
                if (tid == 0) { selIdx[k] = (int)(~(unsigned)mk); selValid[k] = 1; }
                ++k;
            }
        }
    }
    __syncthreads();

    if (tid < MAX_DET)
        sel[grp * MAX_DET + tid] = make_int2(selIdx[tid], selValid[tid]);
}

__global__ __launch_bounds__(1024) void select_nms_kernel(
    const float* __restrict__ confW, const float* __restrict__ boxW,
    int2* __restrict__ sel, LvlParams p0, LvlParams p1, LvlParams p2)
{
    __shared__ float sconf[19200];
    __shared__ unsigned long long sk[MCAP];
    __shared__ unsigned hist[2048];
    __shared__ float sbox[MCAP][4];
    __shared__ int   selIdx[MAX_DET];
    __shared__ int   selValid[MAX_DET];
    __shared__ unsigned wtot[16];
    __shared__ unsigned misc[4];

    int grp = blockIdx.x;
    int lvl = grp >> 4, b = grp & 15;
    if (lvl == 0) {
        long base = p0.candOff + (long)b * p0.npc;
        run_group<19200>(confW + base, boxW, base * 4, sconf, sk, hist, sbox, selIdx, selValid, wtot, misc, grp, sel);
    } else if (lvl == 1) {
        long base = p1.candOff + (long)b * p1.npc;
        run_group<4800>(confW + base, boxW, base * 4, sconf, sk, hist, sbox, selIdx, selValid, wtot, misc, grp, sel);
    } else {
        long base = p2.candOff + (long)b * p2.npc;
        run_group<1200>(confW + base, boxW, base * 4, sconf, sk, hist, sbox, selIdx, selValid, wtot, misc, grp, sel);
    }
}

// ---------------- Gather: one block per output slot (48*25 = 1200 blocks) ----------------
__global__ __launch_bounds__(256) void gather_kernel(
    const int2* __restrict__ sel, float* __restrict__ out,
    LvlParams p0, LvlParams p1, LvlParams p2)
{
    int bid = blockIdx.x;
    int grp = bid / MAX_DET, k = bid - grp * MAX_DET;
    int lvl = grp >> 4, b = grp & 15;
    LvlParams p = (lvl == 0) ? p0 : ((lvl == 1) ? p1 : p2);
    int2 sv = sel[bid];
    long obase = p.outOff + ((long)b * MAX_DET + k) * p.C;
    const int hw = p.ny * p.nx;
    if (sv.y) {
        int rem = sv.x % hw;
        int gy = rem / p.nx, gx = rem - gy * p.nx;
        const float* f = p.feat + (long)b * p.C * hw + (long)gy * p.nx + gx;
        for (int c = threadIdx.x; c < p.C; c += 256)
            out[obase + c] = f[(long)c * hw];
    } else {
        for (int c = threadIdx.x; c < p.C; c += 256)
            out[obase + c] = 0.0f;
    }
}

extern "C" void kernel_launch(void* const* d_in, const int* in_sizes, int n_in,
                              void* d_out, int out_size, void* d_ws, size_t ws_size,
                              hipStream_t stream)
{
    const float* xs[3] = {nullptr, nullptr, nullptr};
    const float* fs[3] = {nullptr, nullptr, nullptr};
    const float* anch  = nullptr;
    for (int i = 0; i < n_in; ++i) {
        const float* p = (const float*)d_in[i];
        switch (in_sizes[i]) {
            case 26112000: xs[0] = p; break;
            case 6528000:  xs[1] = p; break;
            case 1632000:  xs[2] = p; break;
            case 13107200: fs[0] = p; break;
            case 6553600:  fs[1] = p; break;
            case 3276800:  fs[2] = p; break;
            case 18:       anch  = p; break;
        }
    }

    char* wsb = (char*)d_ws;
    float* confW = (float*)wsb;                  // 403200 f32
    float* boxW  = (float*)(wsb + 1612800L);     // 403200 f32x4
    int2*  sel   = (int2*)(wsb + 8064000L);      // 48*25 int2

    decode_all_kernel<<<6300, 256, 0, stream>>>(xs[0], xs[1], xs[2], anch, confW, boxW);

    LvlParams P0{fs[0], 0L,      0L,      19200, 80, 80, 128};
    LvlParams P1{fs[1], 307200L, 51200L,  4800,  40, 40, 256};
    LvlParams P2{fs[2], 384000L, 153600L, 1200,  20, 20, 512};

    select_nms_kernel<<<48, 1024, 0, stream>>>(confW, boxW, sel, P0, P1, P2);
    gather_kernel<<<48 * MAX_DET, 256, 0, stream>>>(sel, (float*)d_out, P0, P1, P2);
}

// Round 7
// 76.047 us; speedup vs baseline: 1.1007x; 1.1007x over previous
//
#include <hip/hip_runtime.h>
#include <math.h>
#include <float.h>

#define MAX_DET 25
#define IOU_THRES 0.7f
#define MAX_WH 7680.0f
#define TOPK 256
#define MCAP 512

__device__ __forceinline__ float sigm(float v) {
#pragma clang fp contract(off)
    return 1.0f / (1.0f + expf(-v));
}

// ---------------- Decode: 16 lanes per candidate, direct global loads ----------------
template<int NY, int NX>
__device__ __forceinline__ void decode_body(
    int bid, const float* __restrict__ x, const float* __restrict__ anch,
    float* __restrict__ confW, float* __restrict__ boxW)
{
#pragma clang fp contract(off)
    constexpr int HW = NY * NX;
    constexpr int NPC = 3 * HW;
    constexpr int N = 16 * NPC;
    int t = bid * 256 + threadIdx.x;
    int g = t >> 4;
    if (g >= N) return;
    int l16 = t & 15;
    const float* row = x + (long)g * 85;

    float bv = -FLT_MAX; int bc = 0;
#pragma unroll
    for (int j = 0; j < 5; ++j) {
        float v = row[5 + l16 + 16 * j];
        if (v > bv) { bv = v; bc = l16 + 16 * j; }
    }
#pragma unroll
    for (int off = 8; off; off >>= 1) {
        float ov = __shfl_xor(bv, off);
        int   oc = __shfl_xor(bc, off);
        if (ov > bv || (ov == bv && oc < bc)) { bv = ov; bc = oc; }
    }
    if (l16 != 0) return;

    float v0 = row[0], v1 = row[1], v2 = row[2], v3 = row[3], v4 = row[4];
    int i   = g % NPC;
    int a   = i / HW;
    int rem = i - a * HW;
    int gy  = rem / NX;
    int gx  = rem - gy * NX;

    float conf = sigm(bv) * sigm(v4);
    float cx = sigm(v0) * 2.0f + ((float)gx - 0.5f);
    float cy = sigm(v1) * 2.0f + ((float)gy - 0.5f);
    float tw = sigm(v2) * 2.0f, th = sigm(v3) * 2.0f;
    float w = (tw * tw) * anch[a * 2 + 0];
    float h = (th * th) * anch[a * 2 + 1];
    float x1 = cx - w / 2.0f, y1 = cy - h / 2.0f;
    float x2 = cx + w / 2.0f, y2 = cy + h / 2.0f;
    float offc = (float)bc * MAX_WH;

    confW[g] = conf;
    *reinterpret_cast<float4*>(boxW + (long)g * 4) =
        make_float4(x1 + offc, y1 + offc, x2 + offc, y2 + offc);
}

__global__ __launch_bounds__(256) void decode_all_kernel(
    const float* __restrict__ x0, const float* __restrict__ x1, const float* __restrict__ x2,
    const float* __restrict__ anch, float* __restrict__ confW, float* __restrict__ boxW)
{
    int bid = blockIdx.x;
    if (bid < 19200)       decode_body<80, 80>(bid,          x0, anch + 0,  confW,          boxW);
    else if (bid < 24000)  decode_body<40, 40>(bid - 19200,  x1, anch + 6,  confW + 307200, boxW + 307200L * 4);
    else                   decode_body<20, 20>(bid - 24000,  x2, anch + 12, confW + 384000, boxW + 384000L * 4);
}

// ---------------- Fused per-group: radix-select + reg-resident NMS ----------------
struct LvlParams {
    const float* feat;
    long candOff;
    long outOff;
    int npc, ny, nx, C;
};

template<int NPC>
__device__ __forceinline__ void run_group(
    const float* __restrict__ gconf, const float* __restrict__ boxW, long base4,
    float* sconf, unsigned long long* sk, unsigned* hist, float (*sbox)[4],
    int* selIdx, int* selValid, unsigned* wtot /*16*/, unsigned* misc /*4*/,
    int grp, int2* __restrict__ sel)
{
#pragma clang fp contract(off)
    const int tid = threadIdx.x;
    const int lane = tid & 63;
    const int wid = tid >> 6;

    // stage conf in LDS (vectorized, coalesced)
    const float4* gc4 = (const float4*)gconf;
    float4* sc4 = (float4*)sconf;
    for (int i = tid; i < NPC / 4; i += 1024) sc4[i] = gc4[i];
    if (tid < MAX_DET) selValid[tid] = 0;
    if (tid == 0) misc[0] = 0;

    // ---- exact top-TOPK threshold via 2-pass radix histogram ----
    unsigned B = 0, B2 = 0, K2 = 0;
    for (int pass = 0; pass < 2; ++pass) {
        for (int i = tid; i < 2048; i += 1024) hist[i] = 0;
        __syncthreads();
        for (int i = tid; i < NPC; i += 1024) {
            unsigned bits = __float_as_uint(sconf[i]);
            if (pass == 0) atomicAdd(&hist[bits >> 19], 1u);
            else if ((bits >> 19) == B) atomicAdd(&hist[(bits >> 8) & 2047u], 1u);
        }
        __syncthreads();
        unsigned part = hist[tid * 2] + hist[tid * 2 + 1];
        unsigned s = part;
#pragma unroll
        for (int d = 1; d < 64; d <<= 1) {
            unsigned v = __shfl_down(s, d);
            if (lane < 64 - d) s += v;
        }
        if (lane == 0) wtot[wid] = s;
        __syncthreads();
        unsigned S = s;
        for (int w = wid + 1; w < 16; ++w) S += wtot[w];
        unsigned Ktgt = (pass == 0) ? TOPK : K2;
        if (S >= Ktgt && S - part < Ktgt) {     // unique crossing thread
            unsigned acc = S - part;
            for (int i = 1; i >= 0; --i) {
                unsigned h = hist[tid * 2 + i];
                acc += h;
                if (acc >= Ktgt) { misc[2] = (unsigned)(tid * 2 + i); misc[3] = acc - h; break; }
            }
        }
        __syncthreads();
        if (pass == 0) { B = misc[2]; K2 = Ktgt - misc[3]; }
        else           { B2 = misc[2]; }
        __syncthreads();
    }
    unsigned T = (B << 19) | (B2 << 8);

    // ---- collect {bits >= T} into LDS key list ----
    for (int i = tid; i < NPC; i += 1024) {
        unsigned bits = __float_as_uint(sconf[i]);
        if (bits >= T) {
            unsigned pos = atomicAdd(&misc[0], 1u);
            if (pos < MCAP)
                sk[pos] = ((unsigned long long)bits << 32) | (unsigned)(~i);
        }
    }
    __syncthreads();
    unsigned cn = misc[0];
    int n = (cn < (unsigned)MCAP) ? (int)cn : MCAP;

    // ---- prefetch boxes for all collected slots ----
    for (int i = tid; i < n; i += 1024) {
        int idx = (int)(~(unsigned)sk[i]);
        const float4 bb4 = *reinterpret_cast<const float4*>(boxW + base4 + (long)idx * 4);
        sbox[i][0] = bb4.x; sbox[i][1] = bb4.y; sbox[i][2] = bb4.z; sbox[i][3] = bb4.w;
    }
    __syncthreads();

    // ---- wave-0 register-resident selection-sort NMS (no block barriers) ----
    if (tid < 64) {
        unsigned long long kreg[8];
#pragma unroll
        for (int j = 0; j < 8; ++j) {
            int s = tid + 64 * j;
            kreg[j] = (s < n) ? sk[s] : 0ULL;
        }
        float ex1 = 0.f, ey1 = 0.f, ex2 = 0.f, ey2 = 0.f;  // lane t holds selected box t
        int k = 0;
        while (k < MAX_DET) {
            // 64-lane argmax over remaining keys (unique -> deterministic; tie conf -> smaller idx)
            unsigned long long mk = kreg[0]; int ms = tid;
#pragma unroll
            for (int j = 1; j < 8; ++j)
                if (kreg[j] > mk) { mk = kreg[j]; ms = tid + 64 * j; }
#pragma unroll
            for (int off = 32; off; off >>= 1) {
                unsigned long long ok = __shfl_xor(mk, off);
                int os = __shfl_xor(ms, off);
                if (ok > mk) { mk = ok; ms = os; }
            }
            if (mk == 0ULL) break;          // exhausted
            // owner removes the winner (static indices only)
#pragma unroll
            for (int j = 0; j < 8; ++j)
                if (ms == tid + 64 * j) kreg[j] = 0ULL;

            float cx1 = sbox[ms][0], cy1 = sbox[ms][1];
            float cx2 = sbox[ms][2], cy2 = sbox[ms][3];
            bool rej = false;
            if (tid < k) {
                float ltx = fmaxf(ex1, cx1), lty = fmaxf(ey1, cy1);
                float rbx = fminf(ex2, cx2), rby = fminf(ey2, cy2);
                float ww = fmaxf(rbx - ltx, 0.0f), hh = fmaxf(rby - lty, 0.0f);
                float inter = ww * hh;
                float area1 = (ex2 - ex1) * (ey2 - ey1);
                float area2 = (cx2 - cx1) * (cy2 - cy1);
                float iou = inter / (area1 + area2 - inter);
                rej = iou > IOU_THRES;
            }
            rej = __any(rej);
            if (!rej) {
                if (tid == k) { ex1 = cx1; ey1 = cy1; ex2 = cx2; ey2 = cy2; }
                if (tid == 0) { selIdx[k] = (int)(~(unsigned)mk); selValid[k] = 1; }
                ++k;
            }
        }
    }
    __syncthreads();

    if (tid < MAX_DET)
        sel[grp * MAX_DET + tid] = make_int2(selIdx[tid], selValid[tid]);
}

__global__ __launch_bounds__(1024) void select_nms_kernel(
    const float* __restrict__ confW, const float* __restrict__ boxW,
    int2* __restrict__ sel, LvlParams p0, LvlParams p1, LvlParams p2)
{
    __shared__ float sconf[19200];
    __shared__ unsigned long long sk[MCAP];
    __shared__ unsigned hist[2048];
    __shared__ float sbox[MCAP][4];
    __shared__ int   selIdx[MAX_DET];
    __shared__ int   selValid[MAX_DET];
    __shared__ unsigned wtot[16];
    __shared__ unsigned misc[4];

    int grp = blockIdx.x;
    int lvl = grp >> 4, b = grp & 15;
    if (lvl == 0) {
        long base = p0.candOff + (long)b * p0.npc;
        run_group<19200>(confW + base, boxW, base * 4, sconf, sk, hist, sbox, selIdx, selValid, wtot, misc, grp, sel);
    } else if (lvl == 1) {
        long base = p1.candOff + (long)b * p1.npc;
        run_group<4800>(confW + base, boxW, base * 4, sconf, sk, hist, sbox, selIdx, selValid, wtot, misc, grp, sel);
    } else {
        long base = p2.candOff + (long)b * p2.npc;
        run_group<1200>(confW + base, boxW, base * 4, sconf, sk, hist, sbox, selIdx, selValid, wtot, misc, grp, sel);
    }
}

// ---------------- Gather: one block per output slot (48*25 = 1200 blocks) ----------------
__global__ __launch_bounds__(256) void gather_kernel(
    const int2* __restrict__ sel, float* __restrict__ out,
    LvlParams p0, LvlParams p1, LvlParams p2)
{
    int bid = blockIdx.x;
    int grp = bid / MAX_DET, k = bid - grp * MAX_DET;
    int lvl = grp >> 4, b = grp & 15;
    LvlParams p = (lvl == 0) ? p0 : ((lvl == 1) ? p1 : p2);
    int2 sv = sel[bid];
    long obase = p.outOff + ((long)b * MAX_DET + k) * p.C;
    const int hw = p.ny * p.nx;
    if (sv.y) {
        int rem = sv.x % hw;
        int gy = rem / p.nx, gx = rem - gy * p.nx;
        const float* f = p.feat + (long)b * p.C * hw + (long)gy * p.nx + gx;
        for (int c = threadIdx.x; c < p.C; c += 256)
            out[obase + c] = f[(long)c * hw];
    } else {
        for (int c = threadIdx.x; c < p.C; c += 256)
            out[obase + c] = 0.0f;
    }
}

extern "C" void kernel_launch(void* const* d_in, const int* in_sizes, int n_in,
                              void* d_out, int out_size, void* d_ws, size_t ws_size,
                              hipStream_t stream)
{
    const float* xs[3] = {nullptr, nullptr, nullptr};
    const float* fs[3] = {nullptr, nullptr, nullptr};
    const float* anch  = nullptr;
    for (int i = 0; i < n_in; ++i) {
        const float* p = (const float*)d_in[i];
        switch (in_sizes[i]) {
            case 26112000: xs[0] = p; break;
            case 6528000:  xs[1] = p; break;
            case 1632000:  xs[2] = p; break;
            case 13107200: fs[0] = p; break;
            case 6553600:  fs[1] = p; break;
            case 3276800:  fs[2] = p; break;
            case 18:       anch  = p; break;
        }
    }

    char* wsb = (char*)d_ws;
    float* confW = (float*)wsb;                  // 403200 f32
    float* boxW  = (float*)(wsb + 1612800L);     // 403200 f32x4
    int2*  sel   = (int2*)(wsb + 8064000L);      // 48*25 int2

    decode_all_kernel<<<25200, 256, 0, stream>>>(xs[0], xs[1], xs[2], anch, confW, boxW);

    LvlParams P0{fs[0], 0L,      0L,      19200, 80, 80, 128};
    LvlParams P1{fs[1], 307200L, 51200L,  4800,  40, 40, 256};
    LvlParams P2{fs[2], 384000L, 153600L, 1200,  20, 20, 512};

    select_nms_kernel<<<48, 1024, 0, stream>>>(confW, boxW, sel, P0, P1, P2);
    gather_kernel<<<48 * MAX_DET, 256, 0, stream>>>(sel, (float*)d_out, P0, P1, P2);
}

// Round 8
// 62.998 us; speedup vs baseline: 1.3286x; 1.2071x over previous
//
#include <hip/hip_runtime.h>
#include <math.h>
#include <float.h>

#define MAX_DET 25
#define IOU_THRES 0.7f
#define MAX_WH 7680.0f
#define TOPK 256
#define MCAP 512

__device__ __forceinline__ float sigm(float v) {
#pragma clang fp contract(off)
    return 1.0f / (1.0f + expf(-v));
}

// ---------------- Decode: 4 lanes per candidate, direct global loads ----------------
// Per wave: 16 candidates. Each lane loads 20 class floats (stride 4) -> high MLP,
// 2-step shuffle argmax, epilogue on 16/64 lanes. Same math as the exact version.
template<int NY, int NX>
__device__ __forceinline__ void decode_body(
    int bid, const float* __restrict__ x, const float* __restrict__ anch,
    float* __restrict__ confW, float* __restrict__ boxW)
{
#pragma clang fp contract(off)
    constexpr int HW = NY * NX;
    constexpr int NPC = 3 * HW;
    int t = bid * 256 + threadIdx.x;
    int g = t >> 2;
    int l4 = t & 3;
    const float* row = x + (long)g * 85;

    // max over 80 class logits; lane l4 owns classes {l4, l4+4, ...} ascending
    float bv = -FLT_MAX; int bc = 0;
#pragma unroll
    for (int j = 0; j < 20; ++j) {
        float v = row[5 + l4 + 4 * j];
        if (v > bv) { bv = v; bc = l4 + 4 * j; }
    }
#pragma unroll
    for (int off = 2; off; off >>= 1) {
        float ov = __shfl_xor(bv, off);
        int   oc = __shfl_xor(bc, off);
        if (ov > bv || (ov == bv && oc < bc)) { bv = ov; bc = oc; }
    }
    if (l4 != 0) return;

    float v0 = row[0], v1 = row[1], v2 = row[2], v3 = row[3], v4 = row[4];
    int i   = g % NPC;
    int a   = i / HW;
    int rem = i - a * HW;
    int gy  = rem / NX;
    int gx  = rem - gy * NX;

    float conf = sigm(bv) * sigm(v4);
    float cx = sigm(v0) * 2.0f + ((float)gx - 0.5f);
    float cy = sigm(v1) * 2.0f + ((float)gy - 0.5f);
    float tw = sigm(v2) * 2.0f, th = sigm(v3) * 2.0f;
    float w = (tw * tw) * anch[a * 2 + 0];
    float h = (th * th) * anch[a * 2 + 1];
    float x1 = cx - w / 2.0f, y1 = cy - h / 2.0f;
    float x2 = cx + w / 2.0f, y2 = cy + h / 2.0f;
    float offc = (float)bc * MAX_WH;

    confW[g] = conf;
    *reinterpret_cast<float4*>(boxW + (long)g * 4) =
        make_float4(x1 + offc, y1 + offc, x2 + offc, y2 + offc);
}

__global__ __launch_bounds__(256) void decode_all_kernel(
    const float* __restrict__ x0, const float* __restrict__ x1, const float* __restrict__ x2,
    const float* __restrict__ anch, float* __restrict__ confW, float* __restrict__ boxW)
{
    int bid = blockIdx.x;
    if (bid < 4800)       decode_body<80, 80>(bid,         x0, anch + 0,  confW,          boxW);
    else if (bid < 6000)  decode_body<40, 40>(bid - 4800,  x1, anch + 6,  confW + 307200, boxW + 307200L * 4);
    else                  decode_body<20, 20>(bid - 6000,  x2, anch + 12, confW + 384000, boxW + 384000L * 4);
}

// ---------------- Fused per-group: radix-select + reg-resident NMS ----------------
struct LvlParams {
    const float* feat;
    long candOff;
    long outOff;
    int npc, ny, nx, C;
};

template<int NPC>
__device__ __forceinline__ void run_group(
    const float* __restrict__ gconf, const float* __restrict__ boxW, long base4,
    float* sconf, unsigned long long* sk, unsigned* hist, float (*sbox)[4],
    int* selIdx, int* selValid, unsigned* wtot /*16*/, unsigned* misc /*4*/,
    int grp, int2* __restrict__ sel)
{
#pragma clang fp contract(off)
    const int tid = threadIdx.x;
    const int lane = tid & 63;
    const int wid = tid >> 6;

    // stage conf in LDS (vectorized, coalesced)
    const float4* gc4 = (const float4*)gconf;
    float4* sc4 = (float4*)sconf;
    for (int i = tid; i < NPC / 4; i += 1024) sc4[i] = gc4[i];
    if (tid < MAX_DET) selValid[tid] = 0;
    if (tid == 0) misc[0] = 0;

    // ---- exact top-TOPK threshold via 2-pass radix histogram ----
    unsigned B = 0, B2 = 0, K2 = 0;
    for (int pass = 0; pass < 2; ++pass) {
        for (int i = tid; i < 2048; i += 1024) hist[i] = 0;
        __syncthreads();
        for (int i = tid; i < NPC; i += 1024) {
            unsigned bits = __float_as_uint(sconf[i]);
            if (pass == 0) atomicAdd(&hist[bits >> 19], 1u);
            else if ((bits >> 19) == B) atomicAdd(&hist[(bits >> 8) & 2047u], 1u);
        }
        __syncthreads();
        unsigned part = hist[tid * 2] + hist[tid * 2 + 1];
        unsigned s = part;
#pragma unroll
        for (int d = 1; d < 64; d <<= 1) {
            unsigned v = __shfl_down(s, d);
            if (lane < 64 - d) s += v;
        }
        if (lane == 0) wtot[wid] = s;
        __syncthreads();
        unsigned S = s;
        for (int w = wid + 1; w < 16; ++w) S += wtot[w];
        unsigned Ktgt = (pass == 0) ? TOPK : K2;
        if (S >= Ktgt && S - part < Ktgt) {     // unique crossing thread
            unsigned acc = S - part;
            for (int i = 1; i >= 0; --i) {
                unsigned h = hist[tid * 2 + i];
                acc += h;
                if (acc >= Ktgt) { misc[2] = (unsigned)(tid * 2 + i); misc[3] = acc - h; break; }
            }
        }
        __syncthreads();
        if (pass == 0) { B = misc[2]; K2 = Ktgt - misc[3]; }
        else           { B2 = misc[2]; }
        __syncthreads();
    }
    unsigned T = (B << 19) | (B2 << 8);

    // ---- collect {bits >= T} into LDS key list ----
    for (int i = tid; i < NPC; i += 1024) {
        unsigned bits = __float_as_uint(sconf[i]);
        if (bits >= T) {
            unsigned pos = atomicAdd(&misc[0], 1u);
            if (pos < MCAP)
                sk[pos] = ((unsigned long long)bits << 32) | (unsigned)(~i);
        }
    }
    __syncthreads();
    unsigned cn = misc[0];
    int n = (cn < (unsigned)MCAP) ? (int)cn : MCAP;

    // ---- prefetch boxes for all collected slots ----
    for (int i = tid; i < n; i += 1024) {
        int idx = (int)(~(unsigned)sk[i]);
        const float4 bb4 = *reinterpret_cast<const float4*>(boxW + base4 + (long)idx * 4);
        sbox[i][0] = bb4.x; sbox[i][1] = bb4.y; sbox[i][2] = bb4.z; sbox[i][3] = bb4.w;
    }
    __syncthreads();

    // ---- wave-0 register-resident selection-sort NMS (no block barriers) ----
    if (tid < 64) {
        unsigned long long kreg[8];
#pragma unroll
        for (int j = 0; j < 8; ++j) {
            int s = tid + 64 * j;
            kreg[j] = (s < n) ? sk[s] : 0ULL;
        }
        float ex1 = 0.f, ey1 = 0.f, ex2 = 0.f, ey2 = 0.f;  // lane t holds selected box t
        int k = 0;
        while (k < MAX_DET) {
            // 64-lane argmax over remaining keys (unique -> deterministic; tie conf -> smaller idx)
            unsigned long long mk = kreg[0]; int ms = tid;
#pragma unroll
            for (int j = 1; j < 8; ++j)
                if (kreg[j] > mk) { mk = kreg[j]; ms = tid + 64 * j; }
#pragma unroll
            for (int off = 32; off; off >>= 1) {
                unsigned long long ok = __shfl_xor(mk, off);
                int os = __shfl_xor(ms, off);
                if (ok > mk) { mk = ok; ms = os; }
            }
            if (mk == 0ULL) break;          // exhausted
            // owner removes the winner (static indices only)
#pragma unroll
            for (int j = 0; j < 8; ++j)
                if (ms == tid + 64 * j) kreg[j] = 0ULL;

            float cx1 = sbox[ms][0], cy1 = sbox[ms][1];
            float cx2 = sbox[ms][2], cy2 = sbox[ms][3];
            bool rej = false;
            if (tid < k) {
                float ltx = fmaxf(ex1, cx1), lty = fmaxf(ey1, cy1);
                float rbx = fminf(ex2, cx2), rby = fminf(ey2, cy2);
                float ww = fmaxf(rbx - ltx, 0.0f), hh = fmaxf(rby - lty, 0.0f);
                float inter = ww * hh;
                float area1 = (ex2 - ex1) * (ey2 - ey1);
                float area2 = (cx2 - cx1) * (cy2 - cy1);
                float iou = inter / (area1 + area2 - inter);
                rej = iou > IOU_THRES;
            }
            rej = __any(rej);
            if (!rej) {
                if (tid == k) { ex1 = cx1; ey1 = cy1; ex2 = cx2; ey2 = cy2; }
                if (tid == 0) { selIdx[k] = (int)(~(unsigned)mk); selValid[k] = 1; }
                ++k;
            }
        }
    }
    __syncthreads();

    if (tid < MAX_DET)
        sel[grp * MAX_DET + tid] = make_int2(selIdx[tid], selValid[tid]);
}

__global__ __launch_bounds__(1024) void select_nms_kernel(
    const float* __restrict__ confW, const float* __restrict__ boxW,
    int2* __restrict__ sel, LvlParams p0, LvlParams p1, LvlParams p2)
{
    __shared__ float sconf[19200];
    __shared__ unsigned long long sk[MCAP];
    __shared__ unsigned hist[2048];
    __shared__ float sbox[MCAP][4];
    __shared__ int   selIdx[MAX_DET];
    __shared__ int   selValid[MAX_DET];
    __shared__ unsigned wtot[16];
    __shared__ unsigned misc[4];

    int grp = blockIdx.x;
    int lvl = grp >> 4, b = grp & 15;
    if (lvl == 0) {
        long base = p0.candOff + (long)b * p0.npc;
        run_group<19200>(confW + base, boxW, base * 4, sconf, sk, hist, sbox, selIdx, selValid, wtot, misc, grp, sel);
    } else if (lvl == 1) {
        long base = p1.candOff + (long)b * p1.npc;
        run_group<4800>(confW + base, boxW, base * 4, sconf, sk, hist, sbox, selIdx, selValid, wtot, misc, grp, sel);
    } else {
        long base = p2.candOff + (long)b * p2.npc;
        run_group<1200>(confW + base, boxW, base * 4, sconf, sk, hist, sbox, selIdx, selValid, wtot, misc, grp, sel);
    }
}

// ---------------- Gather: one block per output slot (48*25 = 1200 blocks) ----------------
__global__ __launch_bounds__(256) void gather_kernel(
    const int2* __restrict__ sel, float* __restrict__ out,
    LvlParams p0, LvlParams p1, LvlParams p2)
{
    int bid = blockIdx.x;
    int grp = bid / MAX_DET, k = bid - grp * MAX_DET;
    int lvl = grp >> 4, b = grp & 15;
    LvlParams p = (lvl == 0) ? p0 : ((lvl == 1) ? p1 : p2);
    int2 sv = sel[bid];
    long obase = p.outOff + ((long)b * MAX_DET + k) * p.C;
    const int hw = p.ny * p.nx;
    if (sv.y) {
        int rem = sv.x % hw;
        int gy = rem / p.nx, gx = rem - gy * p.nx;
        const float* f = p.feat + (long)b * p.C * hw + (long)gy * p.nx + gx;
        for (int c = threadIdx.x; c < p.C; c += 256)
            out[obase + c] = f[(long)c * hw];
    } else {
        for (int c = threadIdx.x; c < p.C; c += 256)
            out[obase + c] = 0.0f;
    }
}

extern "C" void kernel_launch(void* const* d_in, const int* in_sizes, int n_in,
                              void* d_out, int out_size, void* d_ws, size_t ws_size,
                              hipStream_t stream)
{
    const float* xs[3] = {nullptr, nullptr, nullptr};
    const float* fs[3] = {nullptr, nullptr, nullptr};
    const float* anch  = nullptr;
    for (int i = 0; i < n_in; ++i) {
        const float* p = (const float*)d_in[i];
        switch (in_sizes[i]) {
            case 26112000: xs[0] = p; break;
            case 6528000:  xs[1] = p; break;
            case 1632000:  xs[2] = p; break;
            case 13107200: fs[0] = p; break;
            case 6553600:  fs[1] = p; break;
            case 3276800:  fs[2] = p; break;
            case 18:       anch  = p; break;
        }
    }

    char* wsb = (char*)d_ws;
    float* confW = (float*)wsb;                  // 403200 f32
    float* boxW  = (float*)(wsb + 1612800L);     // 403200 f32x4
    int2*  sel   = (int2*)(wsb + 8064000L);      // 48*25 int2

    decode_all_kernel<<<6300, 256, 0, stream>>>(xs[0], xs[1], xs[2], anch, confW, boxW);

    LvlParams P0{fs[0], 0L,      0L,      19200, 80, 80, 128};
    LvlParams P1{fs[1], 307200L, 51200L,  4800,  40, 40, 256};
    LvlParams P2{fs[2], 384000L, 153600L, 1200,  20, 20, 512};

    select_nms_kernel<<<48, 1024, 0, stream>>>(confW, boxW, sel, P0, P1, P2);
    gather_kernel<<<48 * MAX_DET, 256, 0, stream>>>(sel, (float*)d_out, P0, P1, P2);
}

// Round 9
// 61.251 us; speedup vs baseline: 1.3665x; 1.0285x over previous
//
#include <hip/hip_runtime.h>
#include <math.h>
#include <float.h>

#define MAX_DET 25
#define IOU_THRES 0.7f
#define MAX_WH 7680.0f
#define TOPK 256
#define MCAP 512

__device__ __forceinline__ float sigm(float v) {
#pragma clang fp contract(off)
    return 1.0f / (1.0f + expf(-v));
}

// ---------------- Slim decode: conf + argmax class only (4 lanes/candidate) ----------------
__global__ __launch_bounds__(256) void decode_all_kernel(
    const float* __restrict__ x0, const float* __restrict__ x1, const float* __restrict__ x2,
    float* __restrict__ confW, unsigned short* __restrict__ bcW)
{
#pragma clang fp contract(off)
    int t = blockIdx.x * 256 + threadIdx.x;
    int g = t >> 2;          // global candidate id, [0, 403200)
    int l4 = t & 3;
    const float* row;
    if (g < 307200)       row = x0 + (long)g * 85;
    else if (g < 384000)  row = x1 + (long)(g - 307200) * 85;
    else                  row = x2 + (long)(g - 384000) * 85;

    // max over 80 class logits; lane l4 owns classes {l4, l4+4, ...} ascending
    float bv = -FLT_MAX; int bc = 0;
#pragma unroll
    for (int j = 0; j < 20; ++j) {
        float v = row[5 + l4 + 4 * j];
        if (v > bv) { bv = v; bc = l4 + 4 * j; }
    }
#pragma unroll
    for (int off = 2; off; off >>= 1) {
        float ov = __shfl_xor(bv, off);
        int   oc = __shfl_xor(bc, off);
        if (ov > bv || (ov == bv && oc < bc)) { bv = ov; bc = oc; }
    }
    if (l4 != 0) return;

    float v4 = row[4];
    confW[g] = sigm(bv) * sigm(v4);
    bcW[g] = (unsigned short)bc;
}

// ---------------- Fused per-group: radix-select + box recompute + NMS + gather ----------------
struct LvlParams {
    const float* feat;
    const float* x;      // level x base
    long candOff;        // candidate offset of level in confW/bcW
    long outOff;         // float offset of level in d_out
    int C;
};

template<int NY, int NX>
__device__ __forceinline__ void run_group(
    const float* __restrict__ gconf, const unsigned short* __restrict__ gbc,
    const float* __restrict__ xg, const float* __restrict__ anch,
    const float* __restrict__ feat, int C, long outOff, int b,
    float* sconf, unsigned long long* sk, unsigned* hists, float (*sbox)[4],
    int* selIdx, int* selValid, unsigned* wtot /*16*/, unsigned* misc /*4*/,
    float* __restrict__ out)
{
#pragma clang fp contract(off)
    constexpr int HW = NY * NX;
    constexpr int NPC = 3 * HW;
    const int tid = threadIdx.x;
    const int lane = tid & 63;
    const int wid = tid >> 6;

    // stage conf in LDS (vectorized, coalesced)
    const float4* gc4 = (const float4*)gconf;
    float4* sc4 = (float4*)sconf;
    for (int i = tid; i < NPC / 4; i += 1024) sc4[i] = gc4[i];
    if (tid < MAX_DET) selValid[tid] = 0;
    if (tid == 0) misc[0] = 0;

    // ---- exact top-TOPK threshold via 2-pass radix histogram (2 sub-hists) ----
    unsigned B = 0, B2 = 0, K2 = 0;
    for (int pass = 0; pass < 2; ++pass) {
        for (int i = tid; i < 4096; i += 1024) hists[i] = 0;
        __syncthreads();
        for (int i = tid; i < NPC; i += 1024) {
            unsigned bits = __float_as_uint(sconf[i]);
            if (pass == 0) atomicAdd(&hists[((tid & 1) << 11) + (bits >> 19)], 1u);
            else if ((bits >> 19) == B) atomicAdd(&hists[((tid & 1) << 11) + ((bits >> 8) & 2047u)], 1u);
        }
        __syncthreads();
        unsigned part = hists[2 * tid] + hists[2 * tid + 1]
                      + hists[2048 + 2 * tid] + hists[2048 + 2 * tid + 1];
        unsigned s = part;
#pragma unroll
        for (int d = 1; d < 64; d <<= 1) {
            unsigned v = __shfl_down(s, d);
            if (lane < 64 - d) s += v;
        }
        if (lane == 0) wtot[wid] = s;
        __syncthreads();
        unsigned S = s;
        for (int w = wid + 1; w < 16; ++w) S += wtot[w];
        unsigned Ktgt = (pass == 0) ? TOPK : K2;
        if (S >= Ktgt && S - part < Ktgt) {     // unique crossing thread
            unsigned acc = S - part;
            for (int i = 1; i >= 0; --i) {
                int bin = 2 * tid + i;
                unsigned h = hists[bin] + hists[2048 + bin];
                acc += h;
                if (acc >= Ktgt) { misc[2] = (unsigned)bin; misc[3] = acc - h; break; }
            }
        }
        __syncthreads();
        if (pass == 0) { B = misc[2]; K2 = Ktgt - misc[3]; }
        else           { B2 = misc[2]; }
        __syncthreads();
    }
    unsigned T = (B << 19) | (B2 << 8);

    // ---- collect {bits >= T} into LDS key list ----
    for (int i = tid; i < NPC; i += 1024) {
        unsigned bits = __float_as_uint(sconf[i]);
        if (bits >= T) {
            unsigned pos = atomicAdd(&misc[0], 1u);
            if (pos < MCAP)
                sk[pos] = ((unsigned long long)bits << 32) | (unsigned)(~i);
        }
    }
    __syncthreads();
    unsigned cn = misc[0];
    int n = (cn < (unsigned)MCAP) ? (int)cn : MCAP;

    // ---- recompute boxes for collected candidates (bit-identical arithmetic) ----
    for (int i = tid; i < n; i += 1024) {
        int idx = (int)(~(unsigned)sk[i]);
        const float* row = xg + (long)idx * 85;
        float v0 = row[0], v1 = row[1], v2 = row[2], v3 = row[3];
        int bc = (int)gbc[idx];
        int a   = idx / HW;
        int rem = idx - a * HW;
        int gy  = rem / NX;
        int gx  = rem - gy * NX;

        float cx = sigm(v0) * 2.0f + ((float)gx - 0.5f);
        float cy = sigm(v1) * 2.0f + ((float)gy - 0.5f);
        float tw = sigm(v2) * 2.0f, th = sigm(v3) * 2.0f;
        float w = (tw * tw) * anch[a * 2 + 0];
        float h = (th * th) * anch[a * 2 + 1];
        float x1 = cx - w / 2.0f, y1 = cy - h / 2.0f;
        float x2 = cx + w / 2.0f, y2 = cy + h / 2.0f;
        float offc = (float)bc * MAX_WH;
        sbox[i][0] = x1 + offc; sbox[i][1] = y1 + offc;
        sbox[i][2] = x2 + offc; sbox[i][3] = y2 + offc;
    }
    __syncthreads();

    // ---- wave-0 register-resident selection-sort NMS (no block barriers) ----
    if (tid < 64) {
        unsigned long long kreg[8];
#pragma unroll
        for (int j = 0; j < 8; ++j) {
            int s = tid + 64 * j;
            kreg[j] = (s < n) ? sk[s] : 0ULL;
        }
        float ex1 = 0.f, ey1 = 0.f, ex2 = 0.f, ey2 = 0.f;  // lane t holds selected box t
        int k = 0;
        while (k < MAX_DET) {
            unsigned long long mk = kreg[0]; int ms = tid;
#pragma unroll
            for (int j = 1; j < 8; ++j)
                if (kreg[j] > mk) { mk = kreg[j]; ms = tid + 64 * j; }
#pragma unroll
            for (int off = 32; off; off >>= 1) {
                unsigned long long ok = __shfl_xor(mk, off);
                int os = __shfl_xor(ms, off);
                if (ok > mk) { mk = ok; ms = os; }
            }
            if (mk == 0ULL) break;          // exhausted
#pragma unroll
            for (int j = 0; j < 8; ++j)
                if (ms == tid + 64 * j) kreg[j] = 0ULL;

            float cx1 = sbox[ms][0], cy1 = sbox[ms][1];
            float cx2 = sbox[ms][2], cy2 = sbox[ms][3];
            bool rej = false;
            if (tid < k) {
                float ltx = fmaxf(ex1, cx1), lty = fmaxf(ey1, cy1);
                float rbx = fminf(ex2, cx2), rby = fminf(ey2, cy2);
                float ww = fmaxf(rbx - ltx, 0.0f), hh = fmaxf(rby - lty, 0.0f);
                float inter = ww * hh;
                float area1 = (ex2 - ex1) * (ey2 - ey1);
                float area2 = (cx2 - cx1) * (cy2 - cy1);
                float iou = inter / (area1 + area2 - inter);
                rej = iou > IOU_THRES;
            }
            rej = __any(rej);
            if (!rej) {
                if (tid == k) { ex1 = cx1; ey1 = cy1; ex2 = cx2; ey2 = cy2; }
                if (tid == 0) { selIdx[k] = (int)(~(unsigned)mk); selValid[k] = 1; }
                ++k;
            }
        }
    }
    __syncthreads();

    // ---- fused gather: parallel over 25*C output elements ----
    const float* fb = feat + (long)b * C * HW;
    long obase = outOff + (long)b * MAX_DET * C;
    for (int e = tid; e < MAX_DET * C; e += 1024) {
        int k2 = e / C, c = e - k2 * C;
        float val = 0.0f;
        if (selValid[k2]) {
            int idx = selIdx[k2];
            int rem = idx % HW;
            val = fb[(long)c * HW + rem];   // rem = gy*NX + gx
        }
        out[obase + e] = val;
    }
}

__global__ __launch_bounds__(1024) void select_nms_gather_kernel(
    const float* __restrict__ confW, const unsigned short* __restrict__ bcW,
    const float* __restrict__ anch, float* __restrict__ out,
    LvlParams p0, LvlParams p1, LvlParams p2)
{
    __shared__ float sconf[19200];
    __shared__ unsigned long long sk[MCAP];
    __shared__ unsigned hists[4096];
    __shared__ float sbox[MCAP][4];
    __shared__ int   selIdx[MAX_DET];
    __shared__ int   selValid[MAX_DET];
    __shared__ unsigned wtot[16];
    __shared__ unsigned misc[4];

    int grp = blockIdx.x;
    int lvl = grp >> 4, b = grp & 15;
    if (lvl == 0) {
        long base = p0.candOff + (long)b * 19200;
        run_group<80, 80>(confW + base, bcW + base, p0.x + base * 85, anch + 0,
                          p0.feat, p0.C, p0.outOff, b,
                          sconf, sk, hists, sbox, selIdx, selValid, wtot, misc, out);
    } else if (lvl == 1) {
        long base = p1.candOff + (long)b * 4800;
        run_group<40, 40>(confW + base, bcW + base, p1.x + (long)b * 4800 * 85, anch + 6,
                          p1.feat, p1.C, p1.outOff, b,
                          sconf, sk, hists, sbox, selIdx, selValid, wtot, misc, out);
    } else {
        long base = p2.candOff + (long)b * 1200;
        run_group<20, 20>(confW + base, bcW + base, p2.x + (long)b * 1200 * 85, anch + 12,
                          p2.feat, p2.C, p2.outOff, b,
                          sconf, sk, hists, sbox, selIdx, selValid, wtot, misc, out);
    }
}

extern "C" void kernel_launch(void* const* d_in, const int* in_sizes, int n_in,
                              void* d_out, int out_size, void* d_ws, size_t ws_size,
                              hipStream_t stream)
{
    const float* xs[3] = {nullptr, nullptr, nullptr};
    const float* fs[3] = {nullptr, nullptr, nullptr};
    const float* anch  = nullptr;
    for (int i = 0; i < n_in; ++i) {
        const float* p = (const float*)d_in[i];
        switch (in_sizes[i]) {
            case 26112000: xs[0] = p; break;
            case 6528000:  xs[1] = p; break;
            case 1632000:  xs[2] = p; break;
            case 13107200: fs[0] = p; break;
            case 6553600:  fs[1] = p; break;
            case 3276800:  fs[2] = p; break;
            case 18:       anch  = p; break;
        }
    }

    char* wsb = (char*)d_ws;
    float*          confW = (float*)wsb;                    // 403200 f32
    unsigned short* bcW   = (unsigned short*)(wsb + 1612800L); // 403200 u16

    decode_all_kernel<<<6300, 256, 0, stream>>>(xs[0], xs[1], xs[2], confW, bcW);

    // x base for level 0 is xs[0] itself (candOff 0); levels 1/2 use per-image bases inside
    LvlParams P0{fs[0], xs[0] - 0L,        0L,      0L,      128};
    LvlParams P1{fs[1], xs[1],             307200L, 51200L,  256};
    LvlParams P2{fs[2], xs[2],             384000L, 153600L, 512};
    // note: for level 0 run_group uses p0.x + base*85 where base includes candOff=0 -> xs[0]+b*19200*85. correct.

    select_nms_gather_kernel<<<48, 1024, 0, stream>>>(confW, bcW, anch, (float*)d_out, P0, P1, P2);
}